// Round 3
// baseline (281.254 us; speedup 1.0000x reference)
//
#include <hip/hip_runtime.h>
#include <hip/hip_bf16.h>
#include <stdint.h>
#include <math.h>

typedef unsigned short u16;
typedef __attribute__((ext_vector_type(8))) short short8;
typedef __attribute__((ext_vector_type(4))) short short4v;
typedef __attribute__((ext_vector_type(4))) float f32x4;
typedef __attribute__((ext_vector_type(16))) float f32x16;

#define NB 4
#define NS 2048
#define NH 12
#define HD 64
#define ND 768
#define ND3 2304

// scale * log2(e) folded into Q at QKV epilogue
#define QSCALE 0.18033688f

// ---------- helpers ----------
__device__ __forceinline__ u16 f2bf(float f) {
    unsigned int u = __float_as_uint(f);
    unsigned int r = u + 0x7fffu + ((u >> 16) & 1u);
    return (u16)(r >> 16);
}

typedef const __attribute__((address_space(1))) unsigned int gu32;
typedef __attribute__((address_space(3))) unsigned int lu32;
// async global->LDS, 16B per lane; LDS dest = wave-uniform base + lane*16
__device__ __forceinline__ void async16(const void* g, void* l) {
    __builtin_amdgcn_global_load_lds((gu32*)(uintptr_t)g, (lu32*)(uintptr_t)l, 16, 0, 0);
}

// ---------- fused fp32 -> bf16 casts (x, W_qkv, W_out) ----------
#define XN4   1572864
#define WQN4  442368
#define WON4  147456
__global__ __launch_bounds__(256) void castall(const float* __restrict__ x,
                                               const float* __restrict__ wq,
                                               const float* __restrict__ wo,
                                               u16* __restrict__ xb,
                                               u16* __restrict__ wqb,
                                               u16* __restrict__ wob) {
    int i = blockIdx.x * 256 + threadIdx.x;
    const float* s; u16* d; int j;
    if (i < XN4) { s = x; d = xb; j = i; }
    else if (i < XN4 + WQN4) { s = wq; d = wqb; j = i - XN4; }
    else if (i < XN4 + WQN4 + WON4) { s = wo; d = wob; j = i - XN4 - WQN4; }
    else return;
    float4 v = ((const float4*)s)[j];
    ushort4 o;
    o.x = f2bf(v.x); o.y = f2bf(v.y); o.z = f2bf(v.z); o.w = f2bf(v.w);
    ((ushort4*)d)[j] = o;
}

// ---------- QKV GEMM: C[8192][2304] = x_bf16 @ Wqkv_bf16^T + b ----------
// epilogue scatters: Q (pre-scaled by QSCALE) -> Qg[B,H,S,64], K -> Kg[B,H,S,64],
// V -> Vtg[B,H,64,S] (transposed)
__global__ __launch_bounds__(256) void gemm_qkv(const u16* __restrict__ A,
                                                const u16* __restrict__ Bw,
                                                const float* __restrict__ bias,
                                                u16* __restrict__ Qg,
                                                u16* __restrict__ Kg,
                                                u16* __restrict__ Vtg) {
    __shared__ u16 lds[8192]; // A: chunks 0..7 (128x32), B: chunks 8..15
    const int tid = threadIdx.x;
    const int w = tid >> 6, l = tid & 63;
    const int lam = l & 15, quad = l >> 4;
    const int wm = w >> 1, wn = w & 1;
    const int bm = blockIdx.x * 128, bn = blockIdx.y * 128;
    const int K = ND;

    f32x4 acc[4][4];
#pragma unroll
    for (int i = 0; i < 4; i++)
#pragma unroll
        for (int j = 0; j < 4; j++) { f32x4 z = {0.f, 0.f, 0.f, 0.f}; acc[i][j] = z; }

    const u16* gp[4];
    u16* sp[4];
#pragma unroll
    for (int i = 0; i < 4; i++) {
        int c = w * 4 + i;
        if (c < 8) { gp[i] = A + (size_t)(bm + c * 16 + lam) * K + quad * 8; sp[i] = lds + c * 512; }
        else { int nf = c - 8; gp[i] = Bw + (size_t)(bn + nf * 16 + lam) * K + quad * 8; sp[i] = lds + 4096 + nf * 512; }
    }

    for (int k0 = 0; k0 < K; k0 += 32) {
        __syncthreads();
#pragma unroll
        for (int i = 0; i < 4; i++) async16(gp[i] + k0, sp[i]);
        __syncthreads();
        short8 a[4], b[4];
#pragma unroll
        for (int i = 0; i < 4; i++) a[i] = *(const short8*)(lds + (wm * 4 + i) * 512 + l * 8);
#pragma unroll
        for (int i = 0; i < 4; i++) b[i] = *(const short8*)(lds + 4096 + (wn * 4 + i) * 512 + l * 8);
#pragma unroll
        for (int mf = 0; mf < 4; mf++)
#pragma unroll
            for (int nf = 0; nf < 4; nf++)
                acc[mf][nf] = __builtin_amdgcn_mfma_f32_16x16x32_bf16(a[mf], b[nf], acc[mf][nf], 0, 0, 0);
    }

    // epilogue: C row = bm + wm*64 + mf*16 + quad*4 + r ; col = bn + wn*64 + nf*16 + lam
#pragma unroll
    for (int nf = 0; nf < 4; nf++) {
        int n = bn + wn * 64 + nf * 16 + lam;
        float bv = bias[n];
        int hh = n / 192, rem = n % 192;
        int rgn = rem / 64, d = rem % 64; // 0:Q 1:K 2:V  (rgn, hh wave-uniform)
        if (rgn == 2) {
#pragma unroll
            for (int mf = 0; mf < 4; mf++) {
                int m0 = bm + wm * 64 + mf * 16 + quad * 4;
                int bq = m0 >> 11, s0 = m0 & 2047;
                ushort4 o;
                o.x = f2bf(acc[mf][nf][0] + bv);
                o.y = f2bf(acc[mf][nf][1] + bv);
                o.z = f2bf(acc[mf][nf][2] + bv);
                o.w = f2bf(acc[mf][nf][3] + bv);
                *(ushort4*)(Vtg + ((size_t)((bq * NH + hh) * HD + d)) * NS + s0) = o;
            }
        } else {
            u16* dst = (rgn == 0) ? Qg : Kg;
            const float sc = (rgn == 0) ? QSCALE : 1.0f;
#pragma unroll
            for (int mf = 0; mf < 4; mf++)
#pragma unroll
                for (int r = 0; r < 4; r++) {
                    int m = bm + wm * 64 + mf * 16 + quad * 4 + r;
                    int bq = m >> 11, s = m & 2047;
                    dst[((size_t)((bq * NH + hh) * NS + s)) * HD + d] = f2bf((acc[mf][nf][r] + bv) * sc);
                }
        }
    }
}

// ---------- flash attention, P-in-register ----------
// grid: (S/128, B*H). block 128 = 2 waves, each wave owns 64 q rows (2 n-groups of 32).
// St = K.Q^T via 32x32x16 (C-layout: col=q=lane&31, row=kpos=(r&3)+8(r>>2)+4(lane>>5)).
// P = exp2(St) packed in-register: St regs [4t..4t+3] ARE the 32x32x8 A-frag for kpos
// block t (A[m=lane&31][k=4(lane>>5)+j]) -- no LDS round-trip for P.
// O[q][hd] += P.V via 32x32x8, V B-frag read as b64 from Vt LDS tile.
__global__ __launch_bounds__(128, 2) void attn(const u16* __restrict__ Qg,
                                               const u16* __restrict__ Kg,
                                               const u16* __restrict__ Vtg,
                                               u16* __restrict__ ctx) {
    __shared__ u16 kt_lds[8192];  // 16 chunks (kg,s): lane L holds K[kg*32+(L&31)][s*16+(L>>5)*8+0..7]
    __shared__ u16 vt_lds[8192];  // (hdg,t): lane L b64 at hdg*4096+t*256+(L&31)*8+(L>>5)*4
                                  //   = Vt[hdg*32+(L&31)][t*8+4*(L>>5)+0..3]
    __shared__ float linv[128];   // per-wave 64 inv-l values
    const int tid = threadIdx.x;
    const int w = tid >> 6, L = tid & 63;
    const int r5 = L & 31, h = L >> 5;
    const int qt = blockIdx.x, bh = blockIdx.y;
    const int b = bh / NH, hd = bh % NH;
    const u16* Qh = Qg + (size_t)bh * NS * HD;
    const u16* Kh = Kg + (size_t)bh * NS * HD;
    const u16* Vh = Vtg + (size_t)bh * HD * NS;

    const int qbase = qt * 128 + w * 64;

    // Q B-frags (32x32x16): lane holds Q[q=ng*32+r5][kd=s*16+h*8+0..7]
    short8 qf[2][4];
#pragma unroll
    for (int ng = 0; ng < 2; ng++)
#pragma unroll
        for (int s = 0; s < 4; s++)
            qf[ng][s] = *(const short8*)(Qh + (size_t)(qbase + ng * 32 + r5) * HD + s * 16 + h * 8);

    f32x16 ot[2][2];
#pragma unroll
    for (int ng = 0; ng < 2; ng++)
#pragma unroll
        for (int hg = 0; hg < 2; hg++)
#pragma unroll
            for (int r = 0; r < 16; r++) ot[ng][hg][r] = 0.f;
    float lacc[2] = {0.f, 0.f};

    // staging: wave w stages K chunks c=w*8+i (kg=c>>2, s=c&3) and Vt pairs p=w*8+i (hdg=w, T=i)
    const u16* kgp[8];
    const u16* vgp[8];
#pragma unroll
    for (int i = 0; i < 8; i++) {
        int c = w * 8 + i, kg = c >> 2, s = c & 3;
        kgp[i] = Kh + (size_t)(kg * 32 + r5) * HD + s * 16 + h * 8;
        vgp[i] = Vh + (size_t)(w * 32 + r5) * NS + i * 16 + h * 8;
    }

    for (int kt = 0; kt < 16; kt++) {
        __syncthreads();
#pragma unroll
        for (int i = 0; i < 8; i++) { async16(kgp[i], kt_lds + (w * 8 + i) * 512); kgp[i] += 128 * HD; }
#pragma unroll
        for (int i = 0; i < 8; i++) { async16(vgp[i], vt_lds + (w * 8 + i) * 512); vgp[i] += 128; }
        __syncthreads();

#pragma unroll
        for (int kg = 0; kg < 4; kg++) {
            // St for both q-groups over this 32-kpos block
            f32x16 st[2];
#pragma unroll
            for (int r = 0; r < 16; r++) { st[0][r] = 0.f; st[1][r] = 0.f; }
#pragma unroll
            for (int s = 0; s < 4; s++) {
                short8 kf = *(const short8*)(kt_lds + (kg * 4 + s) * 512 + L * 8);
                st[0] = __builtin_amdgcn_mfma_f32_32x32x16_bf16(kf, qf[0][s], st[0], 0, 0, 0);
                st[1] = __builtin_amdgcn_mfma_f32_32x32x16_bf16(kf, qf[1][s], st[1], 0, 0, 0);
            }

            // softmax + pack + PV per 8-kpos step t4 (global step t = kg*4+t4)
#pragma unroll
            for (int t4 = 0; t4 < 4; t4++) {
                short4v pf[2];
#pragma unroll
                for (int ng = 0; ng < 2; ng++) {
                    unsigned int u0 = __float_as_uint(__builtin_amdgcn_exp2f(st[ng][4 * t4 + 0]));
                    unsigned int u1 = __float_as_uint(__builtin_amdgcn_exp2f(st[ng][4 * t4 + 1]));
                    unsigned int u2 = __float_as_uint(__builtin_amdgcn_exp2f(st[ng][4 * t4 + 2]));
                    unsigned int u3 = __float_as_uint(__builtin_amdgcn_exp2f(st[ng][4 * t4 + 3]));
                    lacc[ng] += (__uint_as_float(u0 & 0xffff0000u) + __uint_as_float(u1 & 0xffff0000u)) +
                                (__uint_as_float(u2 & 0xffff0000u) + __uint_as_float(u3 & 0xffff0000u));
                    short4v p;
                    p.x = (short)(u0 >> 16); p.y = (short)(u1 >> 16);
                    p.z = (short)(u2 >> 16); p.w = (short)(u3 >> 16);
                    pf[ng] = p;
                }
                const int t = kg * 4 + t4;
#pragma unroll
                for (int hg = 0; hg < 2; hg++) {
                    short4v vf = *(const short4v*)(vt_lds + hg * 4096 + t * 256 + r5 * 8 + h * 4);
                    ot[0][hg] = __builtin_amdgcn_mfma_f32_32x32x8bf16_1k(pf[0], vf, ot[0][hg], 0, 0, 0);
                    ot[1][hg] = __builtin_amdgcn_mfma_f32_32x32x8bf16_1k(pf[1], vf, ot[1][hg], 0, 0, 0);
                }
            }
        }
    }

    // l reduce across kpos halves (lane L and L^32 hold same q, partial sums)
    float* lp = linv + w * 64;
#pragma unroll
    for (int ng = 0; ng < 2; ng++) {
        float lg = lacc[ng] + __shfl_xor(lacc[ng], 32);
        lp[ng * 32 + r5] = 1.0f / lg;  // lanes L, L+32 write same value: benign
    }
    __builtin_amdgcn_s_waitcnt(0xc07f); // our own LDS writes visible to our reads

    // epilogue: O C-layout: col hd' = r5, row q' = (r&3)+8*(r>>2)+4*h
#pragma unroll
    for (int ng = 0; ng < 2; ng++) {
        float sc[16];
#pragma unroll
        for (int r = 0; r < 16; r++) sc[r] = lp[ng * 32 + (r & 3) + 8 * (r >> 2) + 4 * h];
#pragma unroll
        for (int hg = 0; hg < 2; hg++) {
#pragma unroll
            for (int r = 0; r < 16; r++) {
                int q = qbase + ng * 32 + (r & 3) + 8 * (r >> 2) + 4 * h;
                ctx[(size_t)(b * NS + q) * ND + hd * HD + hg * 32 + r5] = f2bf(ot[ng][hg][r] * sc[r]);
            }
        }
    }
}

// ---------- out projection: out[8192][768] = ctx_bf16 @ Wout_bf16^T + b (fp32 store) ----------
__global__ __launch_bounds__(256) void gemm_out(const u16* __restrict__ A,
                                                const u16* __restrict__ Bw,
                                                const float* __restrict__ bias,
                                                float* __restrict__ out) {
    __shared__ u16 lds[8192];
    const int tid = threadIdx.x;
    const int w = tid >> 6, l = tid & 63;
    const int lam = l & 15, quad = l >> 4;
    const int wm = w >> 1, wn = w & 1;
    const int bm = blockIdx.x * 128, bn = blockIdx.y * 128;
    const int K = ND;

    f32x4 acc[4][4];
#pragma unroll
    for (int i = 0; i < 4; i++)
#pragma unroll
        for (int j = 0; j < 4; j++) { f32x4 z = {0.f, 0.f, 0.f, 0.f}; acc[i][j] = z; }

    const u16* gp[4];
    u16* sp[4];
#pragma unroll
    for (int i = 0; i < 4; i++) {
        int c = w * 4 + i;
        if (c < 8) { gp[i] = A + (size_t)(bm + c * 16 + lam) * K + quad * 8; sp[i] = lds + c * 512; }
        else { int nf = c - 8; gp[i] = Bw + (size_t)(bn + nf * 16 + lam) * K + quad * 8; sp[i] = lds + 4096 + nf * 512; }
    }

    for (int k0 = 0; k0 < K; k0 += 32) {
        __syncthreads();
#pragma unroll
        for (int i = 0; i < 4; i++) async16(gp[i] + k0, sp[i]);
        __syncthreads();
        short8 a[4], b[4];
#pragma unroll
        for (int i = 0; i < 4; i++) a[i] = *(const short8*)(lds + (wm * 4 + i) * 512 + l * 8);
#pragma unroll
        for (int i = 0; i < 4; i++) b[i] = *(const short8*)(lds + 4096 + (wn * 4 + i) * 512 + l * 8);
#pragma unroll
        for (int mf = 0; mf < 4; mf++)
#pragma unroll
            for (int nf = 0; nf < 4; nf++)
                acc[mf][nf] = __builtin_amdgcn_mfma_f32_16x16x32_bf16(a[mf], b[nf], acc[mf][nf], 0, 0, 0);
    }

#pragma unroll
    for (int nf = 0; nf < 4; nf++) {
        int n = bn + wn * 64 + nf * 16 + lam;
        float bv = bias[n];
#pragma unroll
        for (int mf = 0; mf < 4; mf++)
#pragma unroll
            for (int r = 0; r < 4; r++) {
                int m = bm + wm * 64 + mf * 16 + quad * 4 + r;
                out[(size_t)m * ND + n] = acc[mf][nf][r] + bv;
            }
    }
}

extern "C" void kernel_launch(void* const* d_in, const int* in_sizes, int n_in,
                              void* d_out, int out_size, void* d_ws, size_t ws_size,
                              hipStream_t stream) {
    const float* x    = (const float*)d_in[0];
    const float* Wqkv = (const float*)d_in[1];
    const float* bqkv = (const float*)d_in[2];
    const float* Wout = (const float*)d_in[3];
    const float* bout = (const float*)d_in[4];
    float* out = (float*)d_out;

    // workspace carve (bf16 elements)
    u16* p = (u16*)d_ws;
    u16* xb    = p; p += 6291456;  // x bf16 [8192][768]
    u16* wqkvb = p; p += 1769472;  // Wqkv bf16 [2304][768]
    u16* wob   = p; p += 589824;   // Wout bf16 [768][768]
    u16* Qg    = p; p += 6291456;  // [B,H,S,64] (pre-scaled by QSCALE)
    u16* Kg    = p; p += 6291456;  // [B,H,S,64]
    u16* Vtg   = p; p += 6291456;  // [B,H,64,S]
    u16* ctx   = p; p += 6291456;  // [8192][768]

    castall<<<8448, 256, 0, stream>>>(x, Wqkv, Wout, xb, wqkvb, wob);
    gemm_qkv<<<dim3(64, 18), 256, 0, stream>>>(xb, wqkvb, bqkv, Qg, Kg, Vtg);
    attn<<<dim3(16, 48), 128, 0, stream>>>(Qg, Kg, Vtg, ctx);
    gemm_out<<<dim3(64, 6), 256, 0, stream>>>(ctx, wob, bout, out);
}

// Round 4
// 242.166 us; speedup vs baseline: 1.1614x; 1.1614x over previous
//
#include <hip/hip_runtime.h>
#include <hip/hip_bf16.h>
#include <stdint.h>
#include <math.h>

typedef unsigned short u16;
typedef __attribute__((ext_vector_type(8))) short short8;
typedef __attribute__((ext_vector_type(4))) short short4v;
typedef __attribute__((ext_vector_type(4))) float f32x4;
typedef __attribute__((ext_vector_type(16))) float f32x16;

#define NB 4
#define NS 2048
#define NH 12
#define HD 64
#define ND 768
#define ND3 2304

// scale * log2(e) folded into Q at QKV epilogue
#define QSCALE 0.18033688f

// ---------- helpers ----------
__device__ __forceinline__ u16 f2bf(float f) {
    unsigned int u = __float_as_uint(f);
    unsigned int r = u + 0x7fffu + ((u >> 16) & 1u);
    return (u16)(r >> 16);
}

typedef const __attribute__((address_space(1))) unsigned int gu32;
typedef __attribute__((address_space(3))) unsigned int lu32;
// async global->LDS, 16B per lane; LDS dest = wave-uniform base + lane*16
__device__ __forceinline__ void async16(const void* g, void* l) {
    __builtin_amdgcn_global_load_lds((gu32*)(uintptr_t)g, (lu32*)(uintptr_t)l, 16, 0, 0);
}

// ---------- fused fp32 -> bf16 casts (x, W_qkv, W_out) ----------
#define XN4   1572864
#define WQN4  442368
#define WON4  147456
__global__ __launch_bounds__(256) void castall(const float* __restrict__ x,
                                               const float* __restrict__ wq,
                                               const float* __restrict__ wo,
                                               u16* __restrict__ xb,
                                               u16* __restrict__ wqb,
                                               u16* __restrict__ wob) {
    int i = blockIdx.x * 256 + threadIdx.x;
    const float* s; u16* d; int j;
    if (i < XN4) { s = x; d = xb; j = i; }
    else if (i < XN4 + WQN4) { s = wq; d = wqb; j = i - XN4; }
    else if (i < XN4 + WQN4 + WON4) { s = wo; d = wob; j = i - XN4 - WQN4; }
    else return;
    float4 v = ((const float4*)s)[j];
    ushort4 o;
    o.x = f2bf(v.x); o.y = f2bf(v.y); o.z = f2bf(v.z); o.w = f2bf(v.w);
    ((ushort4*)d)[j] = o;
}

// ---------- QKV GEMM: C[8192][2304] = x_bf16 @ Wqkv_bf16^T + b ----------
// 128x192 tiles: grid (64,12) = 768 blocks = exactly 3/CU; each block's n-range
// is one head's [Q64|K64|V64]. Epilogue scatters Q (scaled) -> Qg[B,H,S,64],
// K -> Kg[B,H,S,64], V -> Vtg[B,H,64,S] (transposed).
__global__ __launch_bounds__(256, 3) void gemm_qkv(const u16* __restrict__ A,
                                                   const u16* __restrict__ Bw,
                                                   const float* __restrict__ bias,
                                                   u16* __restrict__ Qg,
                                                   u16* __restrict__ Kg,
                                                   u16* __restrict__ Vtg) {
    __shared__ u16 lds[10240]; // A: chunks 0..7 (128x32), B: chunks 8..19 (192x32)
    const int tid = threadIdx.x;
    const int w = tid >> 6, l = tid & 63;
    const int lam = l & 15, quad = l >> 4;
    const int wm = w >> 1, wn = w & 1;
    const int bm = blockIdx.x * 128;
    const int hh = blockIdx.y;          // head (192 cols per head)
    const int bn = hh * 192;
    const int K = ND;

    f32x4 acc[4][6];
#pragma unroll
    for (int i = 0; i < 4; i++)
#pragma unroll
        for (int j = 0; j < 6; j++) { f32x4 z = {0.f, 0.f, 0.f, 0.f}; acc[i][j] = z; }

    const u16* gp[5];
    u16* sp[5];
#pragma unroll
    for (int i = 0; i < 5; i++) {
        int c = w * 5 + i;
        if (c < 8) { gp[i] = A + (size_t)(bm + c * 16 + lam) * K + quad * 8; sp[i] = lds + c * 512; }
        else { int nf = c - 8; gp[i] = Bw + (size_t)(bn + nf * 16 + lam) * K + quad * 8; sp[i] = lds + 4096 + nf * 512; }
    }

    for (int k0 = 0; k0 < K; k0 += 32) {
        __syncthreads();
#pragma unroll
        for (int i = 0; i < 5; i++) async16(gp[i] + k0, sp[i]);
        __syncthreads();
        short8 a[4];
#pragma unroll
        for (int i = 0; i < 4; i++) a[i] = *(const short8*)(lds + (wm * 4 + i) * 512 + l * 8);
#pragma unroll
        for (int half = 0; half < 2; half++) {
            short8 b[3];
#pragma unroll
            for (int j = 0; j < 3; j++) b[j] = *(const short8*)(lds + 4096 + (wn * 6 + half * 3 + j) * 512 + l * 8);
#pragma unroll
            for (int mf = 0; mf < 4; mf++)
#pragma unroll
                for (int j = 0; j < 3; j++)
                    acc[mf][half * 3 + j] = __builtin_amdgcn_mfma_f32_16x16x32_bf16(a[mf], b[j], acc[mf][half * 3 + j], 0, 0, 0);
        }
    }

    // epilogue: C row m = bm + wm*64 + mf*16 + quad*4 + r ; local col = wn*96 + nf*16 + lam
#pragma unroll
    for (int nf = 0; nf < 6; nf++) {
        int nloc = wn * 96 + nf * 16;       // wave-uniform, multiple of 16
        int rgn = nloc / 64;                // 0:Q 1:K 2:V (uniform; lam<16 never crosses)
        int d = (nloc % 64) + lam;
        float bv = bias[bn + nloc + lam];
        if (rgn == 2) {
#pragma unroll
            for (int mf = 0; mf < 4; mf++) {
                int m0 = bm + wm * 64 + mf * 16 + quad * 4;
                int bq = m0 >> 11, s0 = m0 & 2047;
                ushort4 o;
                o.x = f2bf(acc[mf][nf][0] + bv);
                o.y = f2bf(acc[mf][nf][1] + bv);
                o.z = f2bf(acc[mf][nf][2] + bv);
                o.w = f2bf(acc[mf][nf][3] + bv);
                *(ushort4*)(Vtg + ((size_t)((bq * NH + hh) * HD + d)) * NS + s0) = o;
            }
        } else {
            u16* dst = (rgn == 0) ? Qg : Kg;
            const float sc = (rgn == 0) ? QSCALE : 1.0f;
#pragma unroll
            for (int mf = 0; mf < 4; mf++)
#pragma unroll
                for (int r = 0; r < 4; r++) {
                    int m = bm + wm * 64 + mf * 16 + quad * 4 + r;
                    int bq = m >> 11, s = m & 2047;
                    dst[((size_t)((bq * NH + hh) * NS + s)) * HD + d] = f2bf((acc[mf][nf][r] + bv) * sc);
                }
        }
    }
}

// ---------- flash attention, P-in-register, 4-wave blocks ----------
// grid: 768 1-D; qt = bid/48, bh = bid%48 -> all 16 q-tiles of one bh land on
// XCD bh%8 (48%8==0) for K/V L2 locality. Block 256 = 4 waves, wave owns 32 q.
// St = K.Q^T via 32x32x16 (C: col=q=lane&31, row=kpos=(r&3)+8(r>>2)+4h).
// P = exp2(St) truncated to bf16 in-register: regs [4t..4t+3] form the 32x32x8
// A-frag for kpos step t. O[q][hd] += P.V via 32x32x8bf16_1k.
__global__ __launch_bounds__(256, 3) void attn(const u16* __restrict__ Qg,
                                               const u16* __restrict__ Kg,
                                               const u16* __restrict__ Vtg,
                                               u16* __restrict__ ctx) {
    __shared__ u16 kt_lds[8192];  // 16 chunks (kg,s): lane L holds K[kg*32+(L&31)][s*16+(L>>5)*8+0..7]
    __shared__ u16 vt_lds[8192];  // 16 chunks: lane slot = Vt[(c>>3)*32+(L&31)][(c&7)*16+(L>>5)*8+0..7]
    __shared__ float linv[128];   // per-wave 32 inv-l values
    const int tid = threadIdx.x;
    const int w = tid >> 6, L = tid & 63;
    const int r5 = L & 31, h = L >> 5;
    const int bid = blockIdx.x;
    const int qt = bid / 48, bh = bid % 48;
    const int b = bh / NH, hd = bh % NH;
    const u16* Qh = Qg + (size_t)bh * NS * HD;
    const u16* Kh = Kg + (size_t)bh * NS * HD;
    const u16* Vh = Vtg + (size_t)bh * HD * NS;

    const int qbase = qt * 128 + w * 32;

    // Q B-frags (32x32x16): lane holds Q[q=r5][kd=s*16+h*8+0..7]
    short8 qf[4];
#pragma unroll
    for (int s = 0; s < 4; s++)
        qf[s] = *(const short8*)(Qh + (size_t)(qbase + r5) * HD + s * 16 + h * 8);

    f32x16 ot[2];
#pragma unroll
    for (int hg = 0; hg < 2; hg++)
#pragma unroll
        for (int r = 0; r < 16; r++) ot[hg][r] = 0.f;
    float lacc = 0.f;

    // staging: waves 0-1 stage the 16 K chunks, waves 2-3 the 16 Vt chunks
    const u16* gp[8];
    u16* sp[8];
    int step;
    if (w < 2) {
#pragma unroll
        for (int i = 0; i < 8; i++) {
            int c = w * 8 + i, kg = c >> 2, s = c & 3;
            gp[i] = Kh + (size_t)(kg * 32 + r5) * HD + s * 16 + h * 8;
            sp[i] = kt_lds + c * 512;
        }
        step = 128 * HD;
    } else {
#pragma unroll
        for (int i = 0; i < 8; i++) {
            int c = (w - 2) * 8 + i;
            gp[i] = Vh + (size_t)((c >> 3) * 32 + r5) * NS + (c & 7) * 16 + h * 8;
            sp[i] = vt_lds + c * 512;
        }
        step = 128;
    }

    for (int kt = 0; kt < 16; kt++) {
        __syncthreads();
#pragma unroll
        for (int i = 0; i < 8; i++) { async16(gp[i], sp[i]); gp[i] += step; }
        __syncthreads();

#pragma unroll
        for (int kg = 0; kg < 4; kg++) {
            f32x16 st;
#pragma unroll
            for (int r = 0; r < 16; r++) st[r] = 0.f;
#pragma unroll
            for (int s = 0; s < 4; s++) {
                short8 kf = *(const short8*)(kt_lds + (kg * 4 + s) * 512 + L * 8);
                st = __builtin_amdgcn_mfma_f32_32x32x16_bf16(kf, qf[s], st, 0, 0, 0);
            }

            // softmax + pack + PV per 8-kpos step (global step t = kg*4 + t4)
#pragma unroll
            for (int t4 = 0; t4 < 4; t4++) {
                unsigned int u0 = __float_as_uint(__builtin_amdgcn_exp2f(st[4 * t4 + 0]));
                unsigned int u1 = __float_as_uint(__builtin_amdgcn_exp2f(st[4 * t4 + 1]));
                unsigned int u2 = __float_as_uint(__builtin_amdgcn_exp2f(st[4 * t4 + 2]));
                unsigned int u3 = __float_as_uint(__builtin_amdgcn_exp2f(st[4 * t4 + 3]));
                lacc += (__uint_as_float(u0 & 0xffff0000u) + __uint_as_float(u1 & 0xffff0000u)) +
                        (__uint_as_float(u2 & 0xffff0000u) + __uint_as_float(u3 & 0xffff0000u));
                short4v pf;
                pf.x = (short)(u0 >> 16); pf.y = (short)(u1 >> 16);
                pf.z = (short)(u2 >> 16); pf.w = (short)(u3 >> 16);
                const int t = kg * 4 + t4;
#pragma unroll
                for (int hg = 0; hg < 2; hg++) {
                    short4v vf = *(const short4v*)(vt_lds + hg * 4096 + t * 256 + r5 * 8 + h * 4);
                    ot[hg] = __builtin_amdgcn_mfma_f32_32x32x8bf16_1k(pf, vf, ot[hg], 0, 0, 0);
                }
            }
        }
    }

    // l reduce: lane (q,h) summed kpos half; partner lane L^32 has the other half
    float lg = lacc + __shfl_xor(lacc, 32);
    linv[w * 32 + r5] = 1.0f / lg;   // lanes L, L^32 write same value: benign
    __builtin_amdgcn_s_waitcnt(0xc07f); // our own LDS writes visible to our reads

    // epilogue: O C-layout: col hd' = r5, row q' = (r&3)+8*(r>>2)+4*h
    float sc[16];
#pragma unroll
    for (int r = 0; r < 16; r++) sc[r] = linv[w * 32 + (r & 3) + 8 * (r >> 2) + 4 * h];
#pragma unroll
    for (int hg = 0; hg < 2; hg++) {
#pragma unroll
        for (int r = 0; r < 16; r++) {
            int q = qbase + (r & 3) + 8 * (r >> 2) + 4 * h;
            ctx[(size_t)(b * NS + q) * ND + hd * HD + hg * 32 + r5] = f2bf(ot[hg][r] * sc[r]);
        }
    }
}

// ---------- out projection: out[8192][768] = ctx_bf16 @ Wout_bf16^T + b ----------
// 128x96 tiles: grid (64,8) = 512 blocks = exactly 2/CU.
__global__ __launch_bounds__(256) void gemm_out(const u16* __restrict__ A,
                                                const u16* __restrict__ Bw,
                                                const float* __restrict__ bias,
                                                float* __restrict__ out) {
    __shared__ u16 lds[7168]; // A: chunks 0..7, B: chunks 8..13
    const int tid = threadIdx.x;
    const int w = tid >> 6, l = tid & 63;
    const int lam = l & 15, quad = l >> 4;
    const int wm = w >> 1, wn = w & 1;
    const int bm = blockIdx.x * 128, bn = blockIdx.y * 96;
    const int K = ND;

    f32x4 acc[4][3];
#pragma unroll
    for (int i = 0; i < 4; i++)
#pragma unroll
        for (int j = 0; j < 3; j++) { f32x4 z = {0.f, 0.f, 0.f, 0.f}; acc[i][j] = z; }

    const u16* gp[4];
    u16* sp[4];
    int nact = 0;
#pragma unroll
    for (int i = 0; i < 4; i++) {
        int c = w * 4 + i;
        if (c < 8) { gp[nact] = A + (size_t)(bm + c * 16 + lam) * K + quad * 8; sp[nact] = lds + c * 512; nact++; }
        else if (c < 14) { int nf = c - 8; gp[nact] = Bw + (size_t)(bn + nf * 16 + lam) * K + quad * 8; sp[nact] = lds + 4096 + nf * 512; nact++; }
    }

    for (int k0 = 0; k0 < K; k0 += 32) {
        __syncthreads();
        for (int i = 0; i < nact; i++) async16(gp[i] + k0, sp[i]);
        __syncthreads();
        short8 a[4], b[3];
#pragma unroll
        for (int i = 0; i < 4; i++) a[i] = *(const short8*)(lds + (wm * 4 + i) * 512 + l * 8);
#pragma unroll
        for (int j = 0; j < 3; j++) b[j] = *(const short8*)(lds + 4096 + (wn * 3 + j) * 512 + l * 8);
#pragma unroll
        for (int mf = 0; mf < 4; mf++)
#pragma unroll
            for (int j = 0; j < 3; j++)
                acc[mf][j] = __builtin_amdgcn_mfma_f32_16x16x32_bf16(a[mf], b[j], acc[mf][j], 0, 0, 0);
    }

#pragma unroll
    for (int nf = 0; nf < 3; nf++) {
        int n = bn + wn * 48 + nf * 16 + lam;
        float bv = bias[n];
#pragma unroll
        for (int mf = 0; mf < 4; mf++)
#pragma unroll
            for (int r = 0; r < 4; r++) {
                int m = bm + wm * 64 + mf * 16 + quad * 4 + r;
                out[(size_t)m * ND + n] = acc[mf][nf][r] + bv;
            }
    }
}

extern "C" void kernel_launch(void* const* d_in, const int* in_sizes, int n_in,
                              void* d_out, int out_size, void* d_ws, size_t ws_size,
                              hipStream_t stream) {
    const float* x    = (const float*)d_in[0];
    const float* Wqkv = (const float*)d_in[1];
    const float* bqkv = (const float*)d_in[2];
    const float* Wout = (const float*)d_in[3];
    const float* bout = (const float*)d_in[4];
    float* out = (float*)d_out;

    // workspace carve (bf16 elements)
    u16* p = (u16*)d_ws;
    u16* xb    = p; p += 6291456;  // x bf16 [8192][768]
    u16* wqkvb = p; p += 1769472;  // Wqkv bf16 [2304][768]
    u16* wob   = p; p += 589824;   // Wout bf16 [768][768]
    u16* Qg    = p; p += 6291456;  // [B,H,S,64] (pre-scaled by QSCALE)
    u16* Kg    = p; p += 6291456;  // [B,H,S,64]
    u16* Vtg   = p; p += 6291456;  // [B,H,64,S]
    u16* ctx   = p; p += 6291456;  // [8192][768]

    castall<<<8448, 256, 0, stream>>>(x, Wqkv, Wout, xb, wqkvb, wob);
    gemm_qkv<<<dim3(64, 12), 256, 0, stream>>>(xb, wqkvb, bqkv, Qg, Kg, Vtg);
    attn<<<768, 256, 0, stream>>>(Qg, Kg, Vtg, ctx);
    gemm_out<<<dim3(64, 8), 256, 0, stream>>>(ctx, wob, bout, out);
}

// Round 5
// 235.946 us; speedup vs baseline: 1.1920x; 1.0264x over previous
//
#include <hip/hip_runtime.h>
#include <hip/hip_bf16.h>
#include <stdint.h>
#include <math.h>

typedef unsigned short u16;
typedef __attribute__((ext_vector_type(8))) short short8;
typedef __attribute__((ext_vector_type(4))) short short4v;
typedef __attribute__((ext_vector_type(4))) float f32x4;
typedef __attribute__((ext_vector_type(16))) float f32x16;
typedef __attribute__((ext_vector_type(4))) unsigned int u32x4;

#define NB 4
#define NS 2048
#define NH 12
#define HD 64
#define ND 768
#define ND3 2304

// scale * log2(e) folded into Q at QKV epilogue
#define QSCALE 0.18033688f

// ---------- helpers ----------
__device__ __forceinline__ u16 f2bf(float f) {
    unsigned int u = __float_as_uint(f);
    unsigned int r = u + 0x7fffu + ((u >> 16) & 1u);
    return (u16)(r >> 16);
}

typedef const __attribute__((address_space(1))) unsigned int gu32;
typedef __attribute__((address_space(3))) unsigned int lu32;
// async global->LDS, 16B per lane; LDS dest = wave-uniform base + lane*16
__device__ __forceinline__ void async16(const void* g, void* l) {
    __builtin_amdgcn_global_load_lds((gu32*)(uintptr_t)g, (lu32*)(uintptr_t)l, 16, 0, 0);
}

// ---------- fused fp32 -> bf16 casts (x, W_qkv, W_out) ----------
#define XN4   1572864
#define WQN4  442368
#define WON4  147456
__global__ __launch_bounds__(256) void castall(const float* __restrict__ x,
                                               const float* __restrict__ wq,
                                               const float* __restrict__ wo,
                                               u16* __restrict__ xb,
                                               u16* __restrict__ wqb,
                                               u16* __restrict__ wob) {
    int i = blockIdx.x * 256 + threadIdx.x;
    const float* s; u16* d; int j;
    if (i < XN4) { s = x; d = xb; j = i; }
    else if (i < XN4 + WQN4) { s = wq; d = wqb; j = i - XN4; }
    else if (i < XN4 + WQN4 + WON4) { s = wo; d = wob; j = i - XN4 - WQN4; }
    else return;
    float4 v = ((const float4*)s)[j];
    ushort4 o;
    o.x = f2bf(v.x); o.y = f2bf(v.y); o.z = f2bf(v.z); o.w = f2bf(v.w);
    ((ushort4*)d)[j] = o;
}

// ---------- QKV GEMM: C[8192][2304] = x_bf16 @ Wqkv_bf16^T + b ----------
// 128x192 tiles: grid (64,12) = 768 blocks = exactly 3/CU; each block's n-range
// is one head's [Q64|K64|V64]. Epilogue scatters Q (scaled) -> Qg[B,H,S,64],
// K -> Kg[B,H,S,64], V -> Vtg[B,H,64,S] (transposed).
__global__ __launch_bounds__(256, 3) void gemm_qkv(const u16* __restrict__ A,
                                                   const u16* __restrict__ Bw,
                                                   const float* __restrict__ bias,
                                                   u16* __restrict__ Qg,
                                                   u16* __restrict__ Kg,
                                                   u16* __restrict__ Vtg) {
    __shared__ u16 lds[10240]; // A: chunks 0..7 (128x32), B: chunks 8..19 (192x32)
    const int tid = threadIdx.x;
    const int w = tid >> 6, l = tid & 63;
    const int lam = l & 15, quad = l >> 4;
    const int wm = w >> 1, wn = w & 1;
    const int bm = blockIdx.x * 128;
    const int hh = blockIdx.y;          // head (192 cols per head)
    const int bn = hh * 192;
    const int K = ND;

    f32x4 acc[4][6];
#pragma unroll
    for (int i = 0; i < 4; i++)
#pragma unroll
        for (int j = 0; j < 6; j++) { f32x4 z = {0.f, 0.f, 0.f, 0.f}; acc[i][j] = z; }

    const u16* gp[5];
    u16* sp[5];
#pragma unroll
    for (int i = 0; i < 5; i++) {
        int c = w * 5 + i;
        if (c < 8) { gp[i] = A + (size_t)(bm + c * 16 + lam) * K + quad * 8; sp[i] = lds + c * 512; }
        else { int nf = c - 8; gp[i] = Bw + (size_t)(bn + nf * 16 + lam) * K + quad * 8; sp[i] = lds + 4096 + nf * 512; }
    }

    for (int k0 = 0; k0 < K; k0 += 32) {
        __syncthreads();
#pragma unroll
        for (int i = 0; i < 5; i++) async16(gp[i] + k0, sp[i]);
        __syncthreads();
        short8 a[4];
#pragma unroll
        for (int i = 0; i < 4; i++) a[i] = *(const short8*)(lds + (wm * 4 + i) * 512 + l * 8);
#pragma unroll
        for (int half = 0; half < 2; half++) {
            short8 b[3];
#pragma unroll
            for (int j = 0; j < 3; j++) b[j] = *(const short8*)(lds + 4096 + (wn * 6 + half * 3 + j) * 512 + l * 8);
#pragma unroll
            for (int mf = 0; mf < 4; mf++)
#pragma unroll
                for (int j = 0; j < 3; j++)
                    acc[mf][half * 3 + j] = __builtin_amdgcn_mfma_f32_16x16x32_bf16(a[mf], b[j], acc[mf][half * 3 + j], 0, 0, 0);
        }
    }

    // epilogue: C row m = bm + wm*64 + mf*16 + quad*4 + r ; local col = wn*96 + nf*16 + lam
#pragma unroll
    for (int nf = 0; nf < 6; nf++) {
        int nloc = wn * 96 + nf * 16;       // wave-uniform, multiple of 16
        int rgn = nloc / 64;                // 0:Q 1:K 2:V (uniform; lam<16 never crosses)
        int d = (nloc % 64) + lam;
        float bv = bias[bn + nloc + lam];
        if (rgn == 2) {
#pragma unroll
            for (int mf = 0; mf < 4; mf++) {
                int m0 = bm + wm * 64 + mf * 16 + quad * 4;
                int bq = m0 >> 11, s0 = m0 & 2047;
                ushort4 o;
                o.x = f2bf(acc[mf][nf][0] + bv);
                o.y = f2bf(acc[mf][nf][1] + bv);
                o.z = f2bf(acc[mf][nf][2] + bv);
                o.w = f2bf(acc[mf][nf][3] + bv);
                *(ushort4*)(Vtg + ((size_t)((bq * NH + hh) * HD + d)) * NS + s0) = o;
            }
        } else {
            u16* dst = (rgn == 0) ? Qg : Kg;
            const float sc = (rgn == 0) ? QSCALE : 1.0f;
#pragma unroll
            for (int mf = 0; mf < 4; mf++)
#pragma unroll
                for (int r = 0; r < 4; r++) {
                    int m = bm + wm * 64 + mf * 16 + quad * 4 + r;
                    int bq = m >> 11, s = m & 2047;
                    dst[((size_t)((bq * NH + hh) * NS + s)) * HD + d] = f2bf((acc[mf][nf][r] + bv) * sc);
                }
        }
    }
}

// ---------- flash attention, P-in-register, reg-prefetch pipelined ----------
// grid: 768 1-D; qt = bid/48, bh = bid%48 -> all 16 q-tiles of one bh land on
// XCD bh%8 (48%8==0) for K/V L2 locality. Block 256 = 4 waves, wave owns 32 q.
// K/V tile for kt+1 is loaded into VGPRs during kt's compute; between barriers
// only ds_write_b128 remain (no global-latency drain at the barrier).
// St = K.Q^T via 32x32x16 (C: col=q=lane&31, row=kpos=(r&3)+8(r>>2)+4h).
// P = exp2(St) rounded to bf16 in-register (v_perm pack); l from raw fp32 sum.
// O[q][hd] += P.V via 32x32x8bf16_1k.
__global__ __launch_bounds__(256, 3) void attn(const u16* __restrict__ Qg,
                                               const u16* __restrict__ Kg,
                                               const u16* __restrict__ Vtg,
                                               u16* __restrict__ ctx) {
    __shared__ u16 kt_lds[8192];  // 16 chunks (kg,s): lane L holds K[kg*32+(L&31)][s*16+(L>>5)*8+0..7]
    __shared__ u16 vt_lds[8192];  // 16 chunks: lane slot = Vt[(c>>3)*32+(L&31)][(c&7)*16+(L>>5)*8+0..7]
    __shared__ float linv[128];   // per-wave 32 inv-l values
    const int tid = threadIdx.x;
    const int w = tid >> 6, L = tid & 63;
    const int r5 = L & 31, h = L >> 5;
    const int bid = blockIdx.x;
    const int qt = bid / 48, bh = bid % 48;
    const int b = bh / NH, hd = bh % NH;
    const u16* Qh = Qg + (size_t)bh * NS * HD;
    const u16* Kh = Kg + (size_t)bh * NS * HD;
    const u16* Vh = Vtg + (size_t)bh * HD * NS;

    const int qbase = qt * 128 + w * 32;

    // Q B-frags (32x32x16): lane holds Q[q=r5][kd=s*16+h*8+0..7]
    short8 qf[4];
#pragma unroll
    for (int s = 0; s < 4; s++)
        qf[s] = *(const short8*)(Qh + (size_t)(qbase + r5) * HD + s * 16 + h * 8);

    f32x16 ot[2];
#pragma unroll
    for (int hg = 0; hg < 2; hg++)
#pragma unroll
        for (int r = 0; r < 16; r++) ot[hg][r] = 0.f;
    float lacc = 0.f;

    // staging: waves 0-1 own the 16 K chunks, waves 2-3 the 16 Vt chunks.
    // Per kt, each wave prefetches its 8 chunks (16B/lane) into VGPRs.
    const u16* gp[8];
    u16* sp[8];
    int step;
    if (w < 2) {
#pragma unroll
        for (int i = 0; i < 8; i++) {
            int c = w * 8 + i, kg = c >> 2, s = c & 3;
            gp[i] = Kh + (size_t)(kg * 32 + r5) * HD + s * 16 + h * 8;
            sp[i] = kt_lds + c * 512;
        }
        step = 128 * HD;
    } else {
#pragma unroll
        for (int i = 0; i < 8; i++) {
            int c = (w - 2) * 8 + i;
            gp[i] = Vh + (size_t)((c >> 3) * 32 + r5) * NS + (c & 7) * 16 + h * 8;
            sp[i] = vt_lds + c * 512;
        }
        step = 128;
    }

    // preload tile kt=0
    u32x4 rg[8];
#pragma unroll
    for (int i = 0; i < 8; i++) { rg[i] = *(const u32x4*)gp[i]; gp[i] += step; }

    for (int kt = 0; kt < 16; kt++) {
        __syncthreads();   // prior tile's compute done -> LDS reusable
#pragma unroll
        for (int i = 0; i < 8; i++) *(u32x4*)(sp[i] + (size_t)L * 8) = rg[i];
        __syncthreads();

        // issue next tile's loads now; they complete during this tile's compute
        if (kt < 15) {
#pragma unroll
            for (int i = 0; i < 8; i++) { rg[i] = *(const u32x4*)gp[i]; gp[i] += step; }
        }

#pragma unroll
        for (int kg = 0; kg < 4; kg++) {
            f32x16 st;
#pragma unroll
            for (int r = 0; r < 16; r++) st[r] = 0.f;
#pragma unroll
            for (int s = 0; s < 4; s++) {
                short8 kf = *(const short8*)(kt_lds + (kg * 4 + s) * 512 + L * 8);
                st = __builtin_amdgcn_mfma_f32_32x32x16_bf16(kf, qf[s], st, 0, 0, 0);
            }

            // softmax + pack + PV per 8-kpos step (global step t = kg*4 + t4)
#pragma unroll
            for (int t4 = 0; t4 < 4; t4++) {
                float e0 = __builtin_amdgcn_exp2f(st[4 * t4 + 0]);
                float e1 = __builtin_amdgcn_exp2f(st[4 * t4 + 1]);
                float e2 = __builtin_amdgcn_exp2f(st[4 * t4 + 2]);
                float e3 = __builtin_amdgcn_exp2f(st[4 * t4 + 3]);
                lacc += (e0 + e1) + (e2 + e3);      // l from raw fp32 (exact)
                // round-half-up to bf16, pack pairs with v_perm
                unsigned int u0 = __float_as_uint(e0) + 0x8000u;
                unsigned int u1 = __float_as_uint(e1) + 0x8000u;
                unsigned int u2 = __float_as_uint(e2) + 0x8000u;
                unsigned int u3 = __float_as_uint(e3) + 0x8000u;
                unsigned int pk0 = __builtin_amdgcn_perm(u1, u0, 0x07060302u);
                unsigned int pk1 = __builtin_amdgcn_perm(u3, u2, 0x07060302u);
                short4v pf;
                pf.x = (short)(pk0 & 0xffffu); pf.y = (short)(pk0 >> 16);
                pf.z = (short)(pk1 & 0xffffu); pf.w = (short)(pk1 >> 16);
                const int t = kg * 4 + t4;
#pragma unroll
                for (int hg = 0; hg < 2; hg++) {
                    short4v vf = *(const short4v*)(vt_lds + hg * 4096 + t * 256 + r5 * 8 + h * 4);
                    ot[hg] = __builtin_amdgcn_mfma_f32_32x32x8bf16_1k(pf, vf, ot[hg], 0, 0, 0);
                }
            }
        }
    }

    // l reduce: lane (q,h) summed kpos half; partner lane L^32 has the other half
    float lg = lacc + __shfl_xor(lacc, 32);
    linv[w * 32 + r5] = 1.0f / lg;   // lanes L, L^32 write same value: benign
    __builtin_amdgcn_s_waitcnt(0xc07f); // our own LDS writes visible to our reads

    // epilogue: O C-layout: col hd' = r5, row q' = (r&3)+8*(r>>2)+4*h
    float sc[16];
#pragma unroll
    for (int r = 0; r < 16; r++) sc[r] = linv[w * 32 + (r & 3) + 8 * (r >> 2) + 4 * h];
#pragma unroll
    for (int hg = 0; hg < 2; hg++) {
#pragma unroll
        for (int r = 0; r < 16; r++) {
            int q = qbase + (r & 3) + 8 * (r >> 2) + 4 * h;
            ctx[(size_t)(b * NS + q) * ND + hd * HD + hg * 32 + r5] = f2bf(ot[hg][r] * sc[r]);
        }
    }
}

// ---------- out projection: out[8192][768] = ctx_bf16 @ Wout_bf16^T + b ----------
// 128x96 tiles: grid (64,8) = 512 blocks = exactly 2/CU.
__global__ __launch_bounds__(256) void gemm_out(const u16* __restrict__ A,
                                                const u16* __restrict__ Bw,
                                                const float* __restrict__ bias,
                                                float* __restrict__ out) {
    __shared__ u16 lds[7168]; // A: chunks 0..7, B: chunks 8..13
    const int tid = threadIdx.x;
    const int w = tid >> 6, l = tid & 63;
    const int lam = l & 15, quad = l >> 4;
    const int wm = w >> 1, wn = w & 1;
    const int bm = blockIdx.x * 128, bn = blockIdx.y * 96;
    const int K = ND;

    f32x4 acc[4][3];
#pragma unroll
    for (int i = 0; i < 4; i++)
#pragma unroll
        for (int j = 0; j < 3; j++) { f32x4 z = {0.f, 0.f, 0.f, 0.f}; acc[i][j] = z; }

    const u16* gp[4];
    u16* sp[4];
    int nact = 0;
#pragma unroll
    for (int i = 0; i < 4; i++) {
        int c = w * 4 + i;
        if (c < 8) { gp[nact] = A + (size_t)(bm + c * 16 + lam) * K + quad * 8; sp[nact] = lds + c * 512; nact++; }
        else if (c < 14) { int nf = c - 8; gp[nact] = Bw + (size_t)(bn + nf * 16 + lam) * K + quad * 8; sp[nact] = lds + 4096 + nf * 512; nact++; }
    }

    for (int k0 = 0; k0 < K; k0 += 32) {
        __syncthreads();
        for (int i = 0; i < nact; i++) async16(gp[i] + k0, sp[i]);
        __syncthreads();
        short8 a[4], b[3];
#pragma unroll
        for (int i = 0; i < 4; i++) a[i] = *(const short8*)(lds + (wm * 4 + i) * 512 + l * 8);
#pragma unroll
        for (int j = 0; j < 3; j++) b[j] = *(const short8*)(lds + 4096 + (wn * 3 + j) * 512 + l * 8);
#pragma unroll
        for (int mf = 0; mf < 4; mf++)
#pragma unroll
            for (int j = 0; j < 3; j++)
                acc[mf][j] = __builtin_amdgcn_mfma_f32_16x16x32_bf16(a[mf], b[j], acc[mf][j], 0, 0, 0);
    }

#pragma unroll
    for (int nf = 0; nf < 3; nf++) {
        int n = bn + wn * 48 + nf * 16 + lam;
        float bv = bias[n];
#pragma unroll
        for (int mf = 0; mf < 4; mf++)
#pragma unroll
            for (int r = 0; r < 4; r++) {
                int m = bm + wm * 64 + mf * 16 + quad * 4 + r;
                out[(size_t)m * ND + n] = acc[mf][nf][r] + bv;
            }
    }
}

extern "C" void kernel_launch(void* const* d_in, const int* in_sizes, int n_in,
                              void* d_out, int out_size, void* d_ws, size_t ws_size,
                              hipStream_t stream) {
    const float* x    = (const float*)d_in[0];
    const float* Wqkv = (const float*)d_in[1];
    const float* bqkv = (const float*)d_in[2];
    const float* Wout = (const float*)d_in[3];
    const float* bout = (const float*)d_in[4];
    float* out = (float*)d_out;

    // workspace carve (bf16 elements)
    u16* p = (u16*)d_ws;
    u16* xb    = p; p += 6291456;  // x bf16 [8192][768]
    u16* wqkvb = p; p += 1769472;  // Wqkv bf16 [2304][768]
    u16* wob   = p; p += 589824;   // Wout bf16 [768][768]
    u16* Qg    = p; p += 6291456;  // [B,H,S,64] (pre-scaled by QSCALE)
    u16* Kg    = p; p += 6291456;  // [B,H,S,64]
    u16* Vtg   = p; p += 6291456;  // [B,H,64,S]
    u16* ctx   = p; p += 6291456;  // [8192][768]

    castall<<<8448, 256, 0, stream>>>(x, Wqkv, Wout, xb, wqkvb, wob);
    gemm_qkv<<<dim3(64, 12), 256, 0, stream>>>(xb, wqkvb, bqkv, Qg, Kg, Vtg);
    attn<<<768, 256, 0, stream>>>(Qg, Kg, Vtg, ctx);
    gemm_out<<<dim3(64, 8), 256, 0, stream>>>(ctx, wob, bout, out);
}

// Round 6
// 232.338 us; speedup vs baseline: 1.2105x; 1.0155x over previous
//
#include <hip/hip_runtime.h>
#include <hip/hip_bf16.h>
#include <stdint.h>
#include <math.h>

typedef unsigned short u16;
typedef __attribute__((ext_vector_type(8))) short short8;
typedef __attribute__((ext_vector_type(4))) short short4v;
typedef __attribute__((ext_vector_type(4))) float f32x4;
typedef __attribute__((ext_vector_type(16))) float f32x16;
typedef __attribute__((ext_vector_type(4))) unsigned int u32x4;
typedef __attribute__((ext_vector_type(2))) unsigned int u32x2;

#define NB 4
#define NS 2048
#define NH 12
#define HD 64
#define ND 768
#define ND3 2304

// scale * log2(e) folded into Q at QKV epilogue
#define QSCALE 0.18033688f

// ---------- helpers ----------
__device__ __forceinline__ u16 f2bf(float f) {
    unsigned int u = __float_as_uint(f);
    unsigned int r = u + 0x7fffu + ((u >> 16) & 1u);
    return (u16)(r >> 16);
}

// ---------- fused fp32 -> bf16 casts (x, W_qkv, W_out) ----------
#define XN4   1572864
#define WQN4  442368
#define WON4  147456
__global__ __launch_bounds__(256) void castall(const float* __restrict__ x,
                                               const float* __restrict__ wq,
                                               const float* __restrict__ wo,
                                               u16* __restrict__ xb,
                                               u16* __restrict__ wqb,
                                               u16* __restrict__ wob) {
    int i = blockIdx.x * 256 + threadIdx.x;
    const float* s; u16* d; int j;
    if (i < XN4) { s = x; d = xb; j = i; }
    else if (i < XN4 + WQN4) { s = wq; d = wqb; j = i - XN4; }
    else if (i < XN4 + WQN4 + WON4) { s = wo; d = wob; j = i - XN4 - WQN4; }
    else return;
    float4 v = ((const float4*)s)[j];
    ushort4 o;
    o.x = f2bf(v.x); o.y = f2bf(v.y); o.z = f2bf(v.z); o.w = f2bf(v.w);
    ((ushort4*)d)[j] = o;
}

// ---------- QKV GEMM: C[8192][2304] = x_bf16 @ Wqkv_bf16^T + b ----------
// 128x192 tiles, grid (64,12); reg-prefetch pipelined K-loop (next 32-K slab
// loaded to VGPRs during compute; only ds_writes between barriers -> no
// vmcnt(0) drain). Epilogue scatters Q (scaled) -> Qg, K -> Kg, V -> Vtg^T.
__global__ __launch_bounds__(256, 3) void gemm_qkv(const u16* __restrict__ A,
                                                   const u16* __restrict__ Bw,
                                                   const float* __restrict__ bias,
                                                   u16* __restrict__ Qg,
                                                   u16* __restrict__ Kg,
                                                   u16* __restrict__ Vtg) {
    __shared__ u16 lds[10240]; // A: chunks 0..7 (128x32), B: chunks 8..19 (192x32)
    const int tid = threadIdx.x;
    const int w = tid >> 6, l = tid & 63;
    const int lam = l & 15, quad = l >> 4;
    const int wm = w >> 1, wn = w & 1;
    const int bm = blockIdx.x * 128;
    const int hh = blockIdx.y;          // head (192 cols per head)
    const int bn = hh * 192;
    const int K = ND;

    f32x4 acc[4][6];
#pragma unroll
    for (int i = 0; i < 4; i++)
#pragma unroll
        for (int j = 0; j < 6; j++) { f32x4 z = {0.f, 0.f, 0.f, 0.f}; acc[i][j] = z; }

    const u16* gp[5];
    u16* sp[5];
#pragma unroll
    for (int i = 0; i < 5; i++) {
        int c = w * 5 + i;
        if (c < 8) { gp[i] = A + (size_t)(bm + c * 16 + lam) * K + quad * 8; sp[i] = lds + c * 512; }
        else { int nf = c - 8; gp[i] = Bw + (size_t)(bn + nf * 16 + lam) * K + quad * 8; sp[i] = lds + 4096 + nf * 512; }
    }

    u32x4 rg[5];
#pragma unroll
    for (int i = 0; i < 5; i++) rg[i] = *(const u32x4*)gp[i];

    for (int k0 = 0; k0 < K; k0 += 32) {
        __syncthreads();
#pragma unroll
        for (int i = 0; i < 5; i++) *(u32x4*)(sp[i] + (size_t)l * 8) = rg[i];
        __syncthreads();
        if (k0 + 32 < K) {
#pragma unroll
            for (int i = 0; i < 5; i++) rg[i] = *(const u32x4*)(gp[i] + k0 + 32);
        }
        short8 a[4];
#pragma unroll
        for (int i = 0; i < 4; i++) a[i] = *(const short8*)(lds + (wm * 4 + i) * 512 + l * 8);
#pragma unroll
        for (int half = 0; half < 2; half++) {
            short8 b[3];
#pragma unroll
            for (int j = 0; j < 3; j++) b[j] = *(const short8*)(lds + 4096 + (wn * 6 + half * 3 + j) * 512 + l * 8);
#pragma unroll
            for (int mf = 0; mf < 4; mf++)
#pragma unroll
                for (int j = 0; j < 3; j++)
                    acc[mf][half * 3 + j] = __builtin_amdgcn_mfma_f32_16x16x32_bf16(a[mf], b[j], acc[mf][half * 3 + j], 0, 0, 0);
        }
    }

    // epilogue: C row m = bm + wm*64 + mf*16 + quad*4 + r ; local col = wn*96 + nf*16 + lam
#pragma unroll
    for (int nf = 0; nf < 6; nf++) {
        int nloc = wn * 96 + nf * 16;       // wave-uniform, multiple of 16
        int rgn = nloc / 64;                // 0:Q 1:K 2:V (uniform; lam<16 never crosses)
        int d = (nloc % 64) + lam;
        float bv = bias[bn + nloc + lam];
        if (rgn == 2) {
#pragma unroll
            for (int mf = 0; mf < 4; mf++) {
                int m0 = bm + wm * 64 + mf * 16 + quad * 4;
                int bq = m0 >> 11, s0 = m0 & 2047;
                ushort4 o;
                o.x = f2bf(acc[mf][nf][0] + bv);
                o.y = f2bf(acc[mf][nf][1] + bv);
                o.z = f2bf(acc[mf][nf][2] + bv);
                o.w = f2bf(acc[mf][nf][3] + bv);
                *(ushort4*)(Vtg + ((size_t)((bq * NH + hh) * HD + d)) * NS + s0) = o;
            }
        } else {
            u16* dst = (rgn == 0) ? Qg : Kg;
            const float sc = (rgn == 0) ? QSCALE : 1.0f;
#pragma unroll
            for (int mf = 0; mf < 4; mf++)
#pragma unroll
                for (int r = 0; r < 4; r++) {
                    int m = bm + wm * 64 + mf * 16 + quad * 4 + r;
                    int bq = m >> 11, s = m & 2047;
                    dst[((size_t)((bq * NH + hh) * NS + s)) * HD + d] = f2bf((acc[mf][nf][r] + bv) * sc);
                }
        }
    }
}

// ---------- flash attention, P-in-register, full-rate PV via permlane32_swap ----------
// grid: 768 1-D; qt = bid/48, bh = bid%48 (XCD-local K/V). Block 256 = 4 waves.
// St = K.Q^T via 32x32x16 (C: col=q=lane&31, row=kpos=(r&3)+8(r>>2)+4h).
// P packed to bf16 pairs (8 u32 per 32-t block); v_permlane32_swap_b32
// (vdst.hi <-> vsrc.lo) converts C-layout pairs into 32x32x16 A-frags:
//   swap(q0,q2) -> (e0,e2), swap(q1,q3) -> (e1,e3); frag = {e0,e1,e2,e3}.
// O[q][hd] += P.V via 32x32x16 (full rate), V B-frag = b128 from Vt LDS.
__global__ __launch_bounds__(256, 3) void attn(const u16* __restrict__ Qg,
                                               const u16* __restrict__ Kg,
                                               const u16* __restrict__ Vtg,
                                               u16* __restrict__ ctx) {
    __shared__ u16 kt_lds[8192];  // 16 chunks (kg,s): lane L holds K[kg*32+(L&31)][s*16+(L>>5)*8+0..7]
    __shared__ u16 vt_lds[8192];  // 16 chunks c=(hg,tb): lane L = Vt[(c>>3)*32+(L&31)][(c&7)*16+(L>>5)*8+0..7]
    __shared__ float linv[128];   // per-wave 32 inv-l values
    const int tid = threadIdx.x;
    const int w = tid >> 6, L = tid & 63;
    const int r5 = L & 31, h = L >> 5;
    const int bid = blockIdx.x;
    const int qt = bid / 48, bh = bid % 48;
    const int b = bh / NH, hd = bh % NH;
    const u16* Qh = Qg + (size_t)bh * NS * HD;
    const u16* Kh = Kg + (size_t)bh * NS * HD;
    const u16* Vh = Vtg + (size_t)bh * HD * NS;

    const int qbase = qt * 128 + w * 32;

    // Q B-frags (32x32x16): lane holds Q[q=r5][kd=s*16+h*8+0..7]
    short8 qf[4];
#pragma unroll
    for (int s = 0; s < 4; s++)
        qf[s] = *(const short8*)(Qh + (size_t)(qbase + r5) * HD + s * 16 + h * 8);

    f32x16 ot[2];
#pragma unroll
    for (int hg = 0; hg < 2; hg++)
#pragma unroll
        for (int r = 0; r < 16; r++) ot[hg][r] = 0.f;
    float lacc = 0.f;

    // staging: waves 0-1 own the 16 K chunks, waves 2-3 the 16 Vt chunks.
    const u16* gp[8];
    u16* sp[8];
    int step;
    if (w < 2) {
#pragma unroll
        for (int i = 0; i < 8; i++) {
            int c = w * 8 + i, kg = c >> 2, s = c & 3;
            gp[i] = Kh + (size_t)(kg * 32 + r5) * HD + s * 16 + h * 8;
            sp[i] = kt_lds + c * 512;
        }
        step = 128 * HD;
    } else {
#pragma unroll
        for (int i = 0; i < 8; i++) {
            int c = (w - 2) * 8 + i;
            gp[i] = Vh + (size_t)((c >> 3) * 32 + r5) * NS + (c & 7) * 16 + h * 8;
            sp[i] = vt_lds + c * 512;
        }
        step = 128;
    }

    // preload tile kt=0
    u32x4 rg[8];
#pragma unroll
    for (int i = 0; i < 8; i++) { rg[i] = *(const u32x4*)gp[i]; gp[i] += step; }

    for (int kt = 0; kt < 16; kt++) {
        __syncthreads();   // prior tile's compute done -> LDS reusable
#pragma unroll
        for (int i = 0; i < 8; i++) *(u32x4*)(sp[i] + (size_t)L * 8) = rg[i];
        __syncthreads();

        // issue next tile's loads now; they complete during this tile's compute
        if (kt < 15) {
#pragma unroll
            for (int i = 0; i < 8; i++) { rg[i] = *(const u32x4*)gp[i]; gp[i] += step; }
        }

#pragma unroll
        for (int kg = 0; kg < 4; kg++) {
            f32x16 st;
#pragma unroll
            for (int r = 0; r < 16; r++) st[r] = 0.f;
#pragma unroll
            for (int s = 0; s < 4; s++) {
                short8 kf = *(const short8*)(kt_lds + (kg * 4 + s) * 512 + L * 8);
                st = __builtin_amdgcn_mfma_f32_32x32x16_bf16(kf, qf[s], st, 0, 0, 0);
            }

            // exp2 -> round -> pack pairs: q8[i] = bf16(e[2i]) | bf16(e[2i+1])<<16
            unsigned int q8[8];
#pragma unroll
            for (int i = 0; i < 8; i++) {
                float e0 = __builtin_amdgcn_exp2f(st[2 * i + 0]);
                float e1 = __builtin_amdgcn_exp2f(st[2 * i + 1]);
                lacc += e0 + e1;
                unsigned int u0 = __float_as_uint(e0) + 0x8000u;
                unsigned int u1 = __float_as_uint(e1) + 0x8000u;
                q8[i] = __builtin_amdgcn_perm(u1, u0, 0x07060302u);
            }
            // cross-lane half-swaps -> A-frags for the two 16-t blocks of this kg
            u32x2 s02 = __builtin_amdgcn_permlane32_swap(q8[0], q8[2], false, false);
            u32x2 s13 = __builtin_amdgcn_permlane32_swap(q8[1], q8[3], false, false);
            u32x2 s46 = __builtin_amdgcn_permlane32_swap(q8[4], q8[6], false, false);
            u32x2 s57 = __builtin_amdgcn_permlane32_swap(q8[5], q8[7], false, false);
            union { u32x4 u; short8 s; } af0, af1;
            af0.u = (u32x4){s02.x, s13.x, s02.y, s13.y};
            af1.u = (u32x4){s46.x, s57.x, s46.y, s57.y};

#pragma unroll
            for (int hg = 0; hg < 2; hg++) {
                short8 vf0 = *(const short8*)(vt_lds + (hg * 8 + kg * 2 + 0) * 512 + L * 8);
                short8 vf1 = *(const short8*)(vt_lds + (hg * 8 + kg * 2 + 1) * 512 + L * 8);
                ot[hg] = __builtin_amdgcn_mfma_f32_32x32x16_bf16(af0.s, vf0, ot[hg], 0, 0, 0);
                ot[hg] = __builtin_amdgcn_mfma_f32_32x32x16_bf16(af1.s, vf1, ot[hg], 0, 0, 0);
            }
        }
    }

    // l reduce: lane (q,h) summed kpos half; partner lane L^32 has the other half
    float lg = lacc + __shfl_xor(lacc, 32);
    linv[w * 32 + r5] = 1.0f / lg;   // lanes L, L^32 write same value: benign
    __builtin_amdgcn_s_waitcnt(0xc07f); // our own LDS writes visible to our reads

    // epilogue: O C-layout: col hd' = r5, row q' = (r&3)+8*(r>>2)+4*h
    float sc[16];
#pragma unroll
    for (int r = 0; r < 16; r++) sc[r] = linv[w * 32 + (r & 3) + 8 * (r >> 2) + 4 * h];
#pragma unroll
    for (int hg = 0; hg < 2; hg++) {
#pragma unroll
        for (int r = 0; r < 16; r++) {
            int q = qbase + (r & 3) + 8 * (r >> 2) + 4 * h;
            ctx[(size_t)(b * NS + q) * ND + hd * HD + hg * 32 + r5] = f2bf(ot[hg][r] * sc[r]);
        }
    }
}

// ---------- out projection: out[8192][768] = ctx_bf16 @ Wout_bf16^T + b ----------
// 128x96 tiles, grid (64,8) = 512 blocks = 2/CU; reg-prefetch pipelined K-loop.
// 14 chunks staged by 4 waves x 4 slots; w3's surplus slots duplicate chunks
// 0,1 (same data, same address: benign).
__global__ __launch_bounds__(256) void gemm_out(const u16* __restrict__ A,
                                                const u16* __restrict__ Bw,
                                                const float* __restrict__ bias,
                                                float* __restrict__ out) {
    __shared__ u16 lds[7168]; // A: chunks 0..7, B: chunks 8..13
    const int tid = threadIdx.x;
    const int w = tid >> 6, l = tid & 63;
    const int lam = l & 15, quad = l >> 4;
    const int wm = w >> 1, wn = w & 1;
    const int bm = blockIdx.x * 128, bn = blockIdx.y * 96;
    const int K = ND;

    f32x4 acc[4][3];
#pragma unroll
    for (int i = 0; i < 4; i++)
#pragma unroll
        for (int j = 0; j < 3; j++) { f32x4 z = {0.f, 0.f, 0.f, 0.f}; acc[i][j] = z; }

    const u16* gp[4];
    u16* sp[4];
#pragma unroll
    for (int i = 0; i < 4; i++) {
        int c = w * 4 + i;
        if (c >= 14) c -= 14;   // duplicate-stage chunks 0,1 (benign)
        if (c < 8) { gp[i] = A + (size_t)(bm + c * 16 + lam) * K + quad * 8; sp[i] = lds + c * 512; }
        else { int nf = c - 8; gp[i] = Bw + (size_t)(bn + nf * 16 + lam) * K + quad * 8; sp[i] = lds + 4096 + nf * 512; }
    }

    u32x4 rg[4];
#pragma unroll
    for (int i = 0; i < 4; i++) rg[i] = *(const u32x4*)gp[i];

    for (int k0 = 0; k0 < K; k0 += 32) {
        __syncthreads();
#pragma unroll
        for (int i = 0; i < 4; i++) *(u32x4*)(sp[i] + (size_t)l * 8) = rg[i];
        __syncthreads();
        if (k0 + 32 < K) {
#pragma unroll
            for (int i = 0; i < 4; i++) rg[i] = *(const u32x4*)(gp[i] + k0 + 32);
        }
        short8 a[4], b[3];
#pragma unroll
        for (int i = 0; i < 4; i++) a[i] = *(const short8*)(lds + (wm * 4 + i) * 512 + l * 8);
#pragma unroll
        for (int j = 0; j < 3; j++) b[j] = *(const short8*)(lds + 4096 + (wn * 3 + j) * 512 + l * 8);
#pragma unroll
        for (int mf = 0; mf < 4; mf++)
#pragma unroll
            for (int j = 0; j < 3; j++)
                acc[mf][j] = __builtin_amdgcn_mfma_f32_16x16x32_bf16(a[mf], b[j], acc[mf][j], 0, 0, 0);
    }

#pragma unroll
    for (int nf = 0; nf < 3; nf++) {
        int n = bn + wn * 48 + nf * 16 + lam;
        float bv = bias[n];
#pragma unroll
        for (int mf = 0; mf < 4; mf++)
#pragma unroll
            for (int r = 0; r < 4; r++) {
                int m = bm + wm * 64 + mf * 16 + quad * 4 + r;
                out[(size_t)m * ND + n] = acc[mf][nf][r] + bv;
            }
    }
}

extern "C" void kernel_launch(void* const* d_in, const int* in_sizes, int n_in,
                              void* d_out, int out_size, void* d_ws, size_t ws_size,
                              hipStream_t stream) {
    const float* x    = (const float*)d_in[0];
    const float* Wqkv = (const float*)d_in[1];
    const float* bqkv = (const float*)d_in[2];
    const float* Wout = (const float*)d_in[3];
    const float* bout = (const float*)d_in[4];
    float* out = (float*)d_out;

    // workspace carve (bf16 elements)
    u16* p = (u16*)d_ws;
    u16* xb    = p; p += 6291456;  // x bf16 [8192][768]
    u16* wqkvb = p; p += 1769472;  // Wqkv bf16 [2304][768]
    u16* wob   = p; p += 589824;   // Wout bf16 [768][768]
    u16* Qg    = p; p += 6291456;  // [B,H,S,64] (pre-scaled by QSCALE)
    u16* Kg    = p; p += 6291456;  // [B,H,S,64]
    u16* Vtg   = p; p += 6291456;  // [B,H,64,S]
    u16* ctx   = p; p += 6291456;  // [8192][768]

    castall<<<8448, 256, 0, stream>>>(x, Wqkv, Wout, xb, wqkvb, wob);
    gemm_qkv<<<dim3(64, 12), 256, 0, stream>>>(xb, wqkvb, bqkv, Qg, Kg, Vtg);
    attn<<<768, 256, 0, stream>>>(Qg, Kg, Vtg, ctx);
    gemm_out<<<dim3(64, 8), 256, 0, stream>>>(ctx, wob, bout, out);
}